// Round 17
// baseline (385.737 us; speedup 1.0000x reference)
//
#include <hip/hip_runtime.h>
#include <hip/hip_bf16.h>

typedef __hip_bfloat16 bf16;

#define NT 262144
#define ND 262144
#define EDT 2097152
#define ETT 1048576
#define NSLOT (2*NT)            // [0,NT)=d2t dst slots, [NT,2NT)=tt dst slots
#define NE_TOT (EDT+ETT)        // 3145728
#define NBKT 1024               // coarse buckets, bucket = slot>>9
#define SPB 512                 // slots per bucket
#define BCAP 3072               // per-bucket ebuf capacity (mean ~2048)
#define CH 8192                 // edges per scatter block (32KB stage)
#define NBLK_SCAT (NE_TOT/CH)   // 384
#define NBLK_STEM (NT/256)      // 1024
#define NBLK_MEGA (2*NBLK_STEM + NBLK_SCAT)

// ---- dual-dtype load/store: isbf==1 -> bf16, else fp32 ----
__device__ __forceinline__ float ldf(const void* p, long i, int isbf){
    if (isbf) return __bfloat162float(((const bf16*)p)[i]);
    return ((const float*)p)[i];
}
__device__ __forceinline__ void stf(void* p, int i, float v, int isbf){
    if (isbf) ((bf16*)p)[i] = __float2bfloat16(v);
    else      ((float*)p)[i] = v;
}
__device__ __forceinline__ float fin(float x){
    return (x==x && x>-3e38f && x<3e38f) ? x : 0.f;
}
// ---- bf16x2 pack/unpack ----
__device__ __forceinline__ unsigned pk2(float a, float b){
    bf16 ha = __float2bfloat16(a), hb = __float2bfloat16(b);
    unsigned short ua = *(unsigned short*)&ha, ub = *(unsigned short*)&hb;
    return ((unsigned)ub<<16) | (unsigned)ua;
}
__device__ __forceinline__ float ulo(unsigned u){ return __uint_as_float(u<<16); }
__device__ __forceinline__ float uhi(unsigned u){ return __uint_as_float(u & 0xffff0000u); }

__device__ __forceinline__ float score8(uint4 u, const float* xr, const float* at){
    float s=0.f, m;
    m = ulo(u.x)+xr[0]; m = m>0.f?m:0.2f*m; s += m*at[0];
    m = uhi(u.x)+xr[1]; m = m>0.f?m:0.2f*m; s += m*at[1];
    m = ulo(u.y)+xr[2]; m = m>0.f?m:0.2f*m; s += m*at[2];
    m = uhi(u.y)+xr[3]; m = m>0.f?m:0.2f*m; s += m*at[3];
    m = ulo(u.z)+xr[4]; m = m>0.f?m:0.2f*m; s += m*at[4];
    m = uhi(u.z)+xr[5]; m = m>0.f?m:0.2f*m; s += m*at[5];
    m = ulo(u.w)+xr[6]; m = m>0.f?m:0.2f*m; s += m*at[6];
    m = uhi(u.w)+xr[7]; m = m>0.f?m:0.2f*m; s += m*at[7];
    return s;
}
__device__ __forceinline__ void acc8(uint4 u, float a, float* acc){
    acc[0] += a*ulo(u.x); acc[1] += a*uhi(u.x);
    acc[2] += a*ulo(u.y); acc[3] += a*uhi(u.y);
    acc[4] += a*ulo(u.z); acc[5] += a*uhi(u.z);
    acc[6] += a*ulo(u.w); acc[7] += a*uhi(u.w);
}

// ---------------- setup: detect dtype + init cursors + zero pool/done (1 block) ----------------
__global__ __launch_bounds__(256) void setup_kernel(
    const unsigned* __restrict__ raw, int* __restrict__ flag,
    int* __restrict__ bktCur, float* __restrict__ pool_sums, float* __restrict__ pool_cnt,
    int* __restrict__ done)
{
    __shared__ int cnt;
    int t = threadIdx.x;
    if (t==0) cnt = 0;
    __syncthreads();
    int c = 0;
    for (int i = t; i < 2048; i += 256){
        unsigned w = raw[i];
        unsigned e = (w >> 7) & 0xFFu;
        if (e >= 116u && e <= 134u) c++;
    }
    atomicAdd(&cnt, c);
    #pragma unroll
    for (int j=0;j<4;j++) bktCur[t + j*256] = (t + j*256)*BCAP;
    #pragma unroll
    for (int j=0;j<3;j++) pool_sums[t + j*256] = 0.f;
    if (t < 16) pool_cnt[t] = 0.f;
    if (t == 0) *done = 0;
    __syncthreads();
    if (t==0) *flag = (cnt > 1024) ? 1 : 0;
}

// ---------------- mega kernel: scatter first, then both stems ----------------
// blocks [0,384): scatter   [384,1408): task stem   [1408,2432): data stem
union SmemMega {
    struct { float sW[192], sb[16], sg[16], sbt[16], sWl[512]; } st;   // task stem
    struct { float sW[80],  sb[16], sg[16], sbt[16], sWl[512]; } sd;   // data stem
    struct { int shc[NBKT], sloff[NBKT], slcur[NBKT], spart[256];
             unsigned stage[CH]; } sc;                                  // scatter (45KB, max)
};

__global__ __launch_bounds__(256) void mega_kernel(
    const void* __restrict__ x_tasks, const void* __restrict__ x_data,
    const void* __restrict__ stem_t_W, const void* __restrict__ stem_t_b,
    const void* __restrict__ ln_t_g, const void* __restrict__ ln_t_b,
    const void* __restrict__ stem_d_W, const void* __restrict__ stem_d_b,
    const void* __restrict__ ln_d_g, const void* __restrict__ ln_d_b,
    const void* __restrict__ tt_Wl, const void* __restrict__ dt_Wl,
    float* __restrict__ xt, unsigned* __restrict__ xl_tt, unsigned* __restrict__ xl_dt,
    const int* __restrict__ ei_dt, const int* __restrict__ mask_dt,
    const int* __restrict__ ei_tt,
    int* __restrict__ bktCur, unsigned* __restrict__ ebuf,
    const int* __restrict__ flag)
{
    __shared__ SmemMega sm;
    int t = threadIdx.x;
    int blk = blockIdx.x;

    if (blk < NBLK_SCAT){
        // ---- bucket scatter (LDS-staged), packed edge: src | dloc<<18 ----
        long e0 = (long)blk * CH;
        for (int b=t; b<NBKT; b+=256) sm.sc.shc[b]=0;
        __syncthreads();
        for (int i=t; i<CH; i+=256){
            long e = e0 + i;
            int slot, keep;
            if (e < EDT){ keep = mask_dt[e]; slot = ei_dt[EDT+e]; }
            else { long e2 = e-EDT; keep = 1; slot = NT + ei_tt[ETT+e2]; }
            if (keep) atomicAdd(&sm.sc.shc[slot>>9], 1);
        }
        __syncthreads();
        int b4 = t*4;
        int a0=sm.sc.shc[b4], a1=sm.sc.shc[b4+1], a2=sm.sc.shc[b4+2], a3=sm.sc.shc[b4+3];
        int lsum = a0+a1+a2+a3;
        sm.sc.spart[t] = lsum;
        __syncthreads();
        for (int off=1; off<256; off<<=1){
            int x = sm.sc.spart[t];
            int add = (t>=off) ? sm.sc.spart[t-off] : 0;
            __syncthreads();
            sm.sc.spart[t] = x + add;
            __syncthreads();
        }
        int run = sm.sc.spart[t] - lsum;
        int totKept = sm.sc.spart[255];
        sm.sc.sloff[b4]=run;   sm.sc.slcur[b4]=run;   run+=a0;
        sm.sc.sloff[b4+1]=run; sm.sc.slcur[b4+1]=run; run+=a1;
        sm.sc.sloff[b4+2]=run; sm.sc.slcur[b4+2]=run; run+=a2;
        sm.sc.sloff[b4+3]=run; sm.sc.slcur[b4+3]=run;
        if (a0>0) sm.sc.shc[b4]   = atomicAdd(&bktCur[b4],   a0);
        if (a1>0) sm.sc.shc[b4+1] = atomicAdd(&bktCur[b4+1], a1);
        if (a2>0) sm.sc.shc[b4+2] = atomicAdd(&bktCur[b4+2], a2);
        if (a3>0) sm.sc.shc[b4+3] = atomicAdd(&bktCur[b4+3], a3);
        __syncthreads();
        for (int i=t; i<CH; i+=256){
            long e = e0 + i;
            int slot, keep, s;
            if (e < EDT){ keep = mask_dt[e]; s = ei_dt[e]; slot = ei_dt[EDT+e]; }
            else { long e2 = e-EDT; keep = 1; s = ei_tt[e2]; slot = NT + ei_tt[ETT+e2]; }
            if (keep){
                int b = slot>>9;
                int pos = atomicAdd(&sm.sc.slcur[b], 1);
                sm.sc.stage[pos] = (unsigned)s | ((unsigned)(slot & 511) << 18);
            }
        }
        __syncthreads();
        for (int i=t; i<totKept; i+=256){
            int lo=0, hi=NBKT-1;
            while (lo<hi){ int mid=(lo+hi+1)>>1; if (sm.sc.sloff[mid]<=i) lo=mid; else hi=mid-1; }
            ebuf[sm.sc.shc[lo] + (i - sm.sc.sloff[lo])] = sm.sc.stage[i];
        }
    } else if (blk < NBLK_SCAT + NBLK_STEM){
        // ---- task stem: xt + fused @tt_Wl -> xl_tt ----
        int isbf = *flag;
        if (t < 192) sm.st.sW[t] = ldf(stem_t_W, t, isbf);
        if (t < 16){ sm.st.sb[t]=ldf(stem_t_b,t,isbf); sm.st.sg[t]=ldf(ln_t_g,t,isbf); sm.st.sbt[t]=ldf(ln_t_b,t,isbf); }
        sm.st.sWl[t]     = ldf(tt_Wl, t,     isbf);
        sm.st.sWl[t+256] = ldf(tt_Wl, t+256, isbf);
        __syncthreads();
        long i = (long)(blk - NBLK_SCAT)*256 + t;
        float f[12];
        #pragma unroll
        for (int k=0;k<12;k++) f[k] = ldf(x_tasks, i*12+k, isbf);
        float h[16];
        #pragma unroll
        for (int c=0;c<16;c++){
            float a = sm.st.sb[c];
            #pragma unroll
            for (int k=0;k<12;k++) a += f[k]*sm.st.sW[k*16+c];
            h[c]=a;
        }
        float mu=0.f;
        #pragma unroll
        for (int c=0;c<16;c++) mu += h[c];
        mu *= (1.f/16.f);
        float var=0.f;
        #pragma unroll
        for (int c=0;c<16;c++){ float d=h[c]-mu; var += d*d; }
        var *= (1.f/16.f);
        float inv = rsqrtf(var + 1e-5f);
        float v[16];
        #pragma unroll
        for (int c=0;c<16;c++){
            float y = sm.st.sg[c]*(h[c]-mu)*inv + sm.st.sbt[c];
            v[c] = fin((y>0.f) ? y : 0.01f*y);
        }
        float4* xp = (float4*)(xt + i*16);
        #pragma unroll
        for (int q=0;q<4;q++) xp[q] = make_float4(v[q*4],v[q*4+1],v[q*4+2],v[q*4+3]);
        float o[32];
        #pragma unroll
        for (int c=0;c<32;c++) o[c]=0.f;
        #pragma unroll
        for (int k=0;k<16;k++){
            float xv=v[k];
            #pragma unroll
            for (int c=0;c<32;c++) o[c] += xv*sm.st.sWl[k*32+c];
        }
        #pragma unroll
        for (int c=0;c<32;c++) o[c] = fin(o[c]);
        uint4* op = (uint4*)(xl_tt + i*16);
        #pragma unroll
        for (int q=0;q<4;q++)
            op[q] = make_uint4(pk2(o[q*8],o[q*8+1]), pk2(o[q*8+2],o[q*8+3]),
                               pk2(o[q*8+4],o[q*8+5]), pk2(o[q*8+6],o[q*8+7]));
    } else {
        // ---- data stem: fused @dt_Wl -> xl_dt ----
        int isbf = *flag;
        if (t < 80) sm.sd.sW[t] = ldf(stem_d_W, t, isbf);
        if (t < 16){ sm.sd.sb[t]=ldf(stem_d_b,t,isbf); sm.sd.sg[t]=ldf(ln_d_g,t,isbf); sm.sd.sbt[t]=ldf(ln_d_b,t,isbf); }
        sm.sd.sWl[t]     = ldf(dt_Wl, t,     isbf);
        sm.sd.sWl[t+256] = ldf(dt_Wl, t+256, isbf);
        __syncthreads();
        long i = (long)(blk - NBLK_SCAT - NBLK_STEM)*256 + t;
        float f[5];
        #pragma unroll
        for (int k=0;k<5;k++) f[k] = ldf(x_data, i*5+k, isbf);
        float h[16];
        #pragma unroll
        for (int c=0;c<16;c++){
            float a = sm.sd.sb[c];
            #pragma unroll
            for (int k=0;k<5;k++) a += f[k]*sm.sd.sW[k*16+c];
            h[c]=a;
        }
        float mu=0.f;
        #pragma unroll
        for (int c=0;c<16;c++) mu += h[c];
        mu *= (1.f/16.f);
        float var=0.f;
        #pragma unroll
        for (int c=0;c<16;c++){ float d=h[c]-mu; var += d*d; }
        var *= (1.f/16.f);
        float inv = rsqrtf(var + 1e-5f);
        float v[16];
        #pragma unroll
        for (int c=0;c<16;c++){
            float y = sm.sd.sg[c]*(h[c]-mu)*inv + sm.sd.sbt[c];
            v[c] = (y>0.f) ? y : 0.01f*y;
        }
        float o[32];
        #pragma unroll
        for (int c=0;c<32;c++) o[c]=0.f;
        #pragma unroll
        for (int k=0;k<16;k++){
            float xv=v[k];
            #pragma unroll
            for (int c=0;c<32;c++) o[c] += xv*sm.sd.sWl[k*32+c];
        }
        #pragma unroll
        for (int c=0;c<32;c++) o[c] = fin(o[c]);
        uint4* op = (uint4*)(xl_dt + i*16);
        #pragma unroll
        for (int q=0;q<4;q++)
            op[q] = make_uint4(pk2(o[q*8],o[q*8+1]), pk2(o[q*8+2],o[q*8+3]),
                               pk2(o[q*8+4],o[q*8+5]), pk2(o[q*8+6],o[q*8+7]));
    }
}

// ---------------- phase 2: per-bucket LDS CSR + head-serial GAT aggregation ----------------
__global__ __launch_bounds__(256) void bucket_aggregate_kernel(
    const int* __restrict__ bktCur, const unsigned* __restrict__ ebuf,
    const float* __restrict__ xt,
    const unsigned* __restrict__ xl_dt, const unsigned* __restrict__ xl_tt,
    const void* __restrict__ dt_Wr, const void* __restrict__ tt_Wr,
    const void* __restrict__ dt_att, const void* __restrict__ tt_att,
    float* __restrict__ agg, const int* __restrict__ flag)
{
    __shared__ float sWr[512], satt[32];
    __shared__ int scnt[SPB], soff[SPB], scur[SPB], spart[256];
    __shared__ unsigned slist[BCAP];
    __shared__ float sspill[256*17];
    int t = threadIdx.x;
    int b = blockIdx.x;
    int which = (b >= NBKT/2);
    int isbf = *flag;
    const void* Wr  = which ? tt_Wr  : dt_Wr;
    const void* att = which ? tt_att : dt_att;
    sWr[t]     = ldf(Wr, t,     isbf);
    sWr[t+256] = ldf(Wr, t+256, isbf);
    if (t < 32) satt[t] = ldf(att, t, isbf);
    scnt[t] = 0; scnt[t+256] = 0;
    __syncthreads();
    int base = b*BCAP;
    int ecnt = bktCur[b] - base;
    if (ecnt > BCAP) ecnt = BCAP;
    if (ecnt < 0) ecnt = 0;
    for (int i=t; i<ecnt; i+=256)
        atomicAdd(&scnt[ebuf[base+i] >> 18], 1);
    __syncthreads();
    int c0 = scnt[2*t], c1 = scnt[2*t+1];
    int ls = c0 + c1;
    spart[t] = ls;
    __syncthreads();
    for (int off=1; off<256; off<<=1){
        int x = spart[t];
        int add = (t>=off) ? spart[t-off] : 0;
        __syncthreads();
        spart[t] = x + add;
        __syncthreads();
    }
    int run = spart[t] - ls;
    soff[2*t] = run; scur[2*t] = run;
    soff[2*t+1] = run + c0; scur[2*t+1] = run + c0;
    __syncthreads();
    for (int i=t; i<ecnt; i+=256){
        unsigned p = ebuf[base+i];
        int pos = atomicAdd(&scur[p >> 18], 1);
        slist[pos] = p & 0x3FFFFu;
    }
    __syncthreads();
    const unsigned* xl = which ? xl_tt : xl_dt;
    #pragma unroll 1
    for (int half=0; half<2; half++){
        int dloc = t + half*256;
        long slot = (long)b*SPB + dloc;
        long d = which ? slot - NT : slot;
        int e0 = soff[dloc], e1 = scur[dloc];
        #pragma unroll 1
        for (int head=0; head<2; head++){
            const float4* xp = (const float4*)(xt + d*16);
            float4 x0=xp[0], x1=xp[1], x2=xp[2], x3=xp[3];
            float xtv[16] = {x0.x,x0.y,x0.z,x0.w, x1.x,x1.y,x1.z,x1.w,
                             x2.x,x2.y,x2.z,x2.w, x3.x,x3.y,x3.z,x3.w};
            float xr[16];
            #pragma unroll
            for (int c=0;c<16;c++) xr[c]=0.f;
            #pragma unroll
            for (int k=0;k<16;k++){
                float xv=xtv[k];
                #pragma unroll
                for (int c=0;c<16;c++) xr[c] += xv*sWr[k*32 + head*16 + c];
            }
            const float* at = satt + head*16;
            float acc[16];
            #pragma unroll
            for (int c=0;c<16;c++) acc[c]=0.f;
            float den=0.f;
            for (int e=e0; e<e1; e++){
                long s = slist[e];
                const uint4* p = (const uint4*)(xl + s*16 + head*8);
                uint4 u0 = p[0], u1 = p[1];
                float sc = score8(u0, xr, at) + score8(u1, xr+8, at+8);
                float a = expf(fminf(fin(sc), 60.f));
                den += a;
                acc8(u0, a, acc); acc8(u1, a, acc+8);
            }
            float id = 1.f/fmaxf(den, 1e-16f);
            if (head==0){
                #pragma unroll
                for (int c=0;c<16;c++) sspill[t*17+c] = acc[c]*id;
            } else {
                float4* op = (float4*)(agg + slot*16);
                #pragma unroll
                for (int q=0;q<4;q++){
                    float v[4];
                    #pragma unroll
                    for (int j=0;j<4;j++)
                        v[j] = fin(0.5f*(sspill[t*17+q*4+j] + acc[q*4+j]*id));
                    op[q] = make_float4(v[0],v[1],v[2],v[3]);
                }
            }
        }
    }
}

// ---------------- fuse + pooling + last-block finish ----------------
// vals[48]-via-aliased-pointers replaced by three independent arrays so the
// compiler registerizes them (aliasing pointers into one array forced the
// private array to scratch -> ~100MB hidden traffic).
__global__ __launch_bounds__(256) void fuse_pool_kernel(
    const float* __restrict__ xt,
    const float* __restrict__ agg_dt, const float* __restrict__ agg_tt,
    const void* __restrict__ dt_res, const void* __restrict__ dt_bias,
    const void* __restrict__ tt_res, const void* __restrict__ tt_bias,
    const void* __restrict__ ln1g, const void* __restrict__ ln1b,
    const void* __restrict__ ln2g, const void* __restrict__ ln2b,
    const int* __restrict__ b_tasks, const int* __restrict__ ptrg,
    float* __restrict__ pool_sums, float* __restrict__ pool_cnt,
    int* __restrict__ done,
    void* __restrict__ out, const int* __restrict__ flag)
{
    int isbf = *flag;
    __shared__ float sdt[256], stt[256], sdb[16], stb[16], s1g[16], s1b[16], s2g[16], s2b[16];
    __shared__ float swave[4*48];
    __shared__ int sptr[16];
    __shared__ int s_nonuni;
    __shared__ int s_last;
    int t = threadIdx.x;
    sdt[t] = ldf(dt_res, t, isbf);
    stt[t] = ldf(tt_res, t, isbf);
    if (t < 16){
        sdb[t]=ldf(dt_bias,t,isbf); stb[t]=ldf(tt_bias,t,isbf);
        s1g[t]=ldf(ln1g,t,isbf); s1b[t]=ldf(ln1b,t,isbf);
        s2g[t]=ldf(ln2g,t,isbf); s2b[t]=ldf(ln2b,t,isbf);
        sptr[t]=ptrg[t];
    }
    if (t==0) s_nonuni = 0;
    __syncthreads();
    long i = blockIdx.x*256 + t;
    const float4* xp = (const float4*)(xt + i*16);
    float4 x0=xp[0], x1=xp[1], x2=xp[2], x3=xp[3];
    float xv[16], tupd[16], dupd[16];
    xv[0]=x0.x; xv[1]=x0.y; xv[2]=x0.z; xv[3]=x0.w;
    xv[4]=x1.x; xv[5]=x1.y; xv[6]=x1.z; xv[7]=x1.w;
    xv[8]=x2.x; xv[9]=x2.y; xv[10]=x2.z; xv[11]=x2.w;
    xv[12]=x3.x; xv[13]=x3.y; xv[14]=x3.z; xv[15]=x3.w;
    {
        const float* ag = agg_dt + i*16;
        float v[16];
        #pragma unroll
        for (int c=0;c<16;c++){
            float r = sdb[c];
            #pragma unroll
            for (int k=0;k<16;k++) r += xv[k]*sdt[k*16+c];
            v[c] = fin(ag[c] + r);
        }
        // ln_act16 inlined on separate arrays
        float mu=0.f;
        #pragma unroll
        for (int c=0;c<16;c++) mu += v[c];
        mu *= (1.f/16.f);
        float var=0.f;
        #pragma unroll
        for (int c=0;c<16;c++){ float d=v[c]-mu; var += d*d; }
        var *= (1.f/16.f);
        float inv = rsqrtf(var + 1e-5f);
        #pragma unroll
        for (int c=0;c<16;c++){
            float y = s1g[c]*(v[c]-mu)*inv + s1b[c];
            dupd[c] = fin((y>0.f) ? y : 0.01f*y);
        }
    }
    {
        const float* ag = agg_tt + i*16;
        float v[16];
        #pragma unroll
        for (int c=0;c<16;c++){
            float r = stb[c];
            #pragma unroll
            for (int k=0;k<16;k++) r += xv[k]*stt[k*16+c];
            v[c] = fin(ag[c] + r);
        }
        float mu=0.f;
        #pragma unroll
        for (int c=0;c<16;c++) mu += v[c];
        mu *= (1.f/16.f);
        float var=0.f;
        #pragma unroll
        for (int c=0;c<16;c++){ float d=v[c]-mu; var += d*d; }
        var *= (1.f/16.f);
        float inv = rsqrtf(var + 1e-5f);
        #pragma unroll
        for (int c=0;c<16;c++){
            float y = s2g[c]*(v[c]-mu)*inv + s2b[c];
            tupd[c] = fin((y>0.f) ? y : 0.01f*y);
        }
    }
    #pragma unroll
    for (int j=0;j<16;j++) xv[j] = fin(xv[j]);
    // first-node-per-graph rows straight to output
    #pragma unroll
    for (int g=0; g<16; g++){
        if (i == sptr[g]){
            #pragma unroll
            for (int j=0;j<16;j++){
                stf(out, g*96+j,    xv[j],   isbf);
                stf(out, g*96+16+j, tupd[j], isbf);
                stf(out, g*96+32+j, dupd[j], isbf);
            }
        }
    }
    int gi = b_tasks[i];
    int g0 = b_tasks[blockIdx.x*256];
    if (gi != g0) s_nonuni = 1;
    __syncthreads();
    if (s_nonuni){
        for (int j=0;j<16;j++){
            atomicAdd(&pool_sums[gi*48+j],    xv[j]);
            atomicAdd(&pool_sums[gi*48+16+j], tupd[j]);
            atomicAdd(&pool_sums[gi*48+32+j], dupd[j]);
        }
        atomicAdd(&pool_cnt[gi], 1.f);
    } else {
        int lane = t & 63, wid = t >> 6;
        #pragma unroll
        for (int j=0;j<16;j++){
            float v = xv[j];
            v += __shfl_down(v, 32); v += __shfl_down(v, 16);
            v += __shfl_down(v, 8);  v += __shfl_down(v, 4);
            v += __shfl_down(v, 2);  v += __shfl_down(v, 1);
            if (lane==0) swave[wid*48+j] = v;
        }
        #pragma unroll
        for (int j=0;j<16;j++){
            float v = tupd[j];
            v += __shfl_down(v, 32); v += __shfl_down(v, 16);
            v += __shfl_down(v, 8);  v += __shfl_down(v, 4);
            v += __shfl_down(v, 2);  v += __shfl_down(v, 1);
            if (lane==0) swave[wid*48+16+j] = v;
        }
        #pragma unroll
        for (int j=0;j<16;j++){
            float v = dupd[j];
            v += __shfl_down(v, 32); v += __shfl_down(v, 16);
            v += __shfl_down(v, 8);  v += __shfl_down(v, 4);
            v += __shfl_down(v, 2);  v += __shfl_down(v, 1);
            if (lane==0) swave[wid*48+32+j] = v;
        }
        __syncthreads();
        if (t < 48){
            float s = swave[t] + swave[48+t] + swave[96+t] + swave[144+t];
            atomicAdd(&pool_sums[g0*48+t], s);
        }
        if (t == 0) atomicAdd(&pool_cnt[g0], 256.f);
    }
    // last-block-done: final block computes the 768 pooled means
    __syncthreads();
    if (t == 0){
        __threadfence();
        s_last = (atomicAdd(done, 1) == gridDim.x - 1) ? 1 : 0;
    }
    __syncthreads();
    if (s_last){
        __threadfence();
        for (int j = t; j < 768; j += 256){
            int g = j/48, c = j - g*48;
            stf(out, g*96+48+c, fin(pool_sums[g*48+c]/fmaxf(pool_cnt[g],1.f)), isbf);
        }
    }
}

extern "C" void kernel_launch(void* const* d_in, const int* in_sizes, int n_in,
                              void* d_out, int out_size, void* d_ws, size_t ws_size,
                              hipStream_t stream)
{
    const void* x_tasks  = d_in[0];
    const void* x_data   = d_in[1];
    const void* stem_t_W = d_in[2];
    const void* stem_t_b = d_in[3];
    const void* stem_d_W = d_in[4];
    const void* stem_d_b = d_in[5];
    const void* ln_t_g   = d_in[6];
    const void* ln_t_b   = d_in[7];
    const void* ln_d_g   = d_in[8];
    const void* ln_d_b   = d_in[9];
    const void* dt_Wl    = d_in[10];
    const void* dt_Wr    = d_in[11];
    const void* dt_att   = d_in[12];
    const void* dt_res   = d_in[13];
    const void* dt_bias  = d_in[14];
    const void* tt_Wl    = d_in[15];
    const void* tt_Wr    = d_in[16];
    const void* tt_att   = d_in[17];
    const void* tt_res   = d_in[18];
    const void* tt_bias  = d_in[19];
    const void* ln1_g    = d_in[20];
    const void* ln1_b    = d_in[21];
    const void* ln2_g    = d_in[22];
    const void* ln2_b    = d_in[23];
    const int*  ei_dt    = (const int*)d_in[24];
    const int*  mask_dt  = (const int*)d_in[25];
    const int*  ei_tt    = (const int*)d_in[26];
    const int*  b_tasks  = (const int*)d_in[27];
    const int*  ptrg     = (const int*)d_in[28];

    char* w = (char*)d_ws;
    const size_t MB = 1ull<<20;
    float*    xt        = (float*)(w);              // 16 MB  [NT,16] fp32
    unsigned* xl_dt     = (unsigned*)(w + 16*MB);   // 16 MB  [ND,16] bf16x2-packed
    unsigned* xl_tt     = (unsigned*)(w + 32*MB);   // 16 MB  [NT,16] bf16x2-packed
    float*    agg       = (float*)(w + 48*MB);      // 32 MB  [NSLOT,16] fp32
    unsigned* ebuf      = (unsigned*)(w + 80*MB);   // 12 MB (NBKT*BCAP) + slack
    int*      bktCur    = (int*)  (w + 93*MB);      // 4 KB
    float*    pool_sums = (float*)(w + 93*MB + 8192);
    float*    pool_cnt  = (float*)(w + 93*MB + 12288);
    int*      flag      = (int*)  (w + 93*MB + 16384);
    int*      done      = (int*)  (w + 93*MB + 16388);

    setup_kernel<<<1, 256, 0, stream>>>((const unsigned*)x_tasks, flag, bktCur,
                                        pool_sums, pool_cnt, done);

    // mega: scatter first (overlaps with stems backfilling behind it)
    mega_kernel<<<NBLK_MEGA, 256, 0, stream>>>(
        x_tasks, x_data, stem_t_W, stem_t_b, ln_t_g, ln_t_b,
        stem_d_W, stem_d_b, ln_d_g, ln_d_b, tt_Wl, dt_Wl,
        xt, xl_tt, xl_dt, ei_dt, mask_dt, ei_tt, bktCur, ebuf, flag);

    // per-bucket LDS CSR + head-serial aggregation (both graphs)
    bucket_aggregate_kernel<<<NBKT, 256, 0, stream>>>(bktCur, ebuf, xt, xl_dt, xl_tt,
        dt_Wr, tt_Wr, dt_att, tt_att, agg, flag);

    // fuse + pool + output (finish folded in via last-block-done)
    fuse_pool_kernel<<<NT/256, 256, 0, stream>>>(xt, agg, agg + (long)NT*16,
        dt_res, dt_bias, tt_res, tt_bias, ln1_g, ln1_b, ln2_g, ln2_b,
        b_tasks, ptrg, pool_sums, pool_cnt, done, d_out, flag);
}

// Round 18
// 382.039 us; speedup vs baseline: 1.0097x; 1.0097x over previous
//
#include <hip/hip_runtime.h>
#include <hip/hip_bf16.h>

typedef __hip_bfloat16 bf16;

#define NT 262144
#define ND 262144
#define EDT 2097152
#define ETT 1048576
#define NSLOT (2*NT)            // [0,NT)=d2t dst slots, [NT,2NT)=tt dst slots
#define NE_TOT (EDT+ETT)        // 3145728
#define NBKT 1024               // coarse buckets, bucket = slot>>9
#define SPB 512                 // slots per bucket
#define BCAP 3072               // per-bucket ebuf capacity (mean ~2048)
#define CH 4096                 // edges per scatter block (16KB stage, ~29KB LDS -> 5 blocks/CU)
#define NBLK_SCAT (NE_TOT/CH)   // 768
#define NBLK_STEM (NT/256)      // 1024
#define NBLK_MEGA (2*NBLK_STEM + NBLK_SCAT)

// ---- dual-dtype load/store: isbf==1 -> bf16, else fp32 ----
__device__ __forceinline__ float ldf(const void* p, long i, int isbf){
    if (isbf) return __bfloat162float(((const bf16*)p)[i]);
    return ((const float*)p)[i];
}
__device__ __forceinline__ void stf(void* p, int i, float v, int isbf){
    if (isbf) ((bf16*)p)[i] = __float2bfloat16(v);
    else      ((float*)p)[i] = v;
}
__device__ __forceinline__ float fin(float x){
    return (x==x && x>-3e38f && x<3e38f) ? x : 0.f;
}
// ---- bf16x2 pack/unpack ----
__device__ __forceinline__ unsigned pk2(float a, float b){
    bf16 ha = __float2bfloat16(a), hb = __float2bfloat16(b);
    unsigned short ua = *(unsigned short*)&ha, ub = *(unsigned short*)&hb;
    return ((unsigned)ub<<16) | (unsigned)ua;
}
__device__ __forceinline__ float ulo(unsigned u){ return __uint_as_float(u<<16); }
__device__ __forceinline__ float uhi(unsigned u){ return __uint_as_float(u & 0xffff0000u); }
__device__ __forceinline__ void unp8(uint4 u, float* o){
    o[0]=ulo(u.x); o[1]=uhi(u.x); o[2]=ulo(u.y); o[3]=uhi(u.y);
    o[4]=ulo(u.z); o[5]=uhi(u.z); o[6]=ulo(u.w); o[7]=uhi(u.w);
}

__device__ __forceinline__ float score8(uint4 u, const float* xr, const float* at){
    float s=0.f, m;
    m = ulo(u.x)+xr[0]; m = m>0.f?m:0.2f*m; s += m*at[0];
    m = uhi(u.x)+xr[1]; m = m>0.f?m:0.2f*m; s += m*at[1];
    m = ulo(u.y)+xr[2]; m = m>0.f?m:0.2f*m; s += m*at[2];
    m = uhi(u.y)+xr[3]; m = m>0.f?m:0.2f*m; s += m*at[3];
    m = ulo(u.z)+xr[4]; m = m>0.f?m:0.2f*m; s += m*at[4];
    m = uhi(u.z)+xr[5]; m = m>0.f?m:0.2f*m; s += m*at[5];
    m = ulo(u.w)+xr[6]; m = m>0.f?m:0.2f*m; s += m*at[6];
    m = uhi(u.w)+xr[7]; m = m>0.f?m:0.2f*m; s += m*at[7];
    return s;
}
__device__ __forceinline__ void acc8(uint4 u, float a, float* acc){
    acc[0] += a*ulo(u.x); acc[1] += a*uhi(u.x);
    acc[2] += a*ulo(u.y); acc[3] += a*uhi(u.y);
    acc[4] += a*ulo(u.z); acc[5] += a*uhi(u.z);
    acc[6] += a*ulo(u.w); acc[7] += a*uhi(u.w);
}

// ---------------- setup: detect dtype + init cursors + zero pool/done (1 block) ----------------
__global__ __launch_bounds__(256) void setup_kernel(
    const unsigned* __restrict__ raw, int* __restrict__ flag,
    int* __restrict__ bktCur, float* __restrict__ pool_sums, float* __restrict__ pool_cnt,
    int* __restrict__ done)
{
    __shared__ int cnt;
    int t = threadIdx.x;
    if (t==0) cnt = 0;
    __syncthreads();
    int c = 0;
    for (int i = t; i < 2048; i += 256){
        unsigned w = raw[i];
        unsigned e = (w >> 7) & 0xFFu;
        if (e >= 116u && e <= 134u) c++;
    }
    atomicAdd(&cnt, c);
    #pragma unroll
    for (int j=0;j<4;j++) bktCur[t + j*256] = (t + j*256)*BCAP;
    #pragma unroll
    for (int j=0;j<3;j++) pool_sums[t + j*256] = 0.f;
    if (t < 16) pool_cnt[t] = 0.f;
    if (t == 0) *done = 0;
    __syncthreads();
    if (t==0) *flag = (cnt > 1024) ? 1 : 0;
}

// ---------------- mega kernel: scatter first, then both stems ----------------
// blocks [0,768): scatter   [768,1792): task stem   [1792,2816): data stem
union SmemMega {
    struct { float sW[192], sb[16], sg[16], sbt[16], sWl[512]; } st;   // task stem
    struct { float sW[80],  sb[16], sg[16], sbt[16], sWl[512]; } sd;   // data stem
    struct { int shc[NBKT], sloff[NBKT], slcur[NBKT], spart[256];
             unsigned stage[CH]; } sc;                                  // scatter (~29KB, max)
};

__global__ __launch_bounds__(256) void mega_kernel(
    const void* __restrict__ x_tasks, const void* __restrict__ x_data,
    const void* __restrict__ stem_t_W, const void* __restrict__ stem_t_b,
    const void* __restrict__ ln_t_g, const void* __restrict__ ln_t_b,
    const void* __restrict__ stem_d_W, const void* __restrict__ stem_d_b,
    const void* __restrict__ ln_d_g, const void* __restrict__ ln_d_b,
    const void* __restrict__ tt_Wl, const void* __restrict__ dt_Wl,
    float* __restrict__ xt, unsigned* __restrict__ xl_tt, unsigned* __restrict__ xl_dt,
    const int* __restrict__ ei_dt, const int* __restrict__ mask_dt,
    const int* __restrict__ ei_tt,
    int* __restrict__ bktCur, unsigned* __restrict__ ebuf,
    const int* __restrict__ flag)
{
    __shared__ SmemMega sm;
    int t = threadIdx.x;
    int blk = blockIdx.x;

    if (blk < NBLK_SCAT){
        // ---- bucket scatter (LDS-staged), packed edge: src | dloc<<18 ----
        long e0 = (long)blk * CH;
        for (int b=t; b<NBKT; b+=256) sm.sc.shc[b]=0;
        __syncthreads();
        for (int i=t; i<CH; i+=256){
            long e = e0 + i;
            int slot, keep;
            if (e < EDT){ keep = mask_dt[e]; slot = ei_dt[EDT+e]; }
            else { long e2 = e-EDT; keep = 1; slot = NT + ei_tt[ETT+e2]; }
            if (keep) atomicAdd(&sm.sc.shc[slot>>9], 1);
        }
        __syncthreads();
        int b4 = t*4;
        int a0=sm.sc.shc[b4], a1=sm.sc.shc[b4+1], a2=sm.sc.shc[b4+2], a3=sm.sc.shc[b4+3];
        int lsum = a0+a1+a2+a3;
        sm.sc.spart[t] = lsum;
        __syncthreads();
        for (int off=1; off<256; off<<=1){
            int x = sm.sc.spart[t];
            int add = (t>=off) ? sm.sc.spart[t-off] : 0;
            __syncthreads();
            sm.sc.spart[t] = x + add;
            __syncthreads();
        }
        int run = sm.sc.spart[t] - lsum;
        int totKept = sm.sc.spart[255];
        sm.sc.sloff[b4]=run;   sm.sc.slcur[b4]=run;   run+=a0;
        sm.sc.sloff[b4+1]=run; sm.sc.slcur[b4+1]=run; run+=a1;
        sm.sc.sloff[b4+2]=run; sm.sc.slcur[b4+2]=run; run+=a2;
        sm.sc.sloff[b4+3]=run; sm.sc.slcur[b4+3]=run;
        if (a0>0) sm.sc.shc[b4]   = atomicAdd(&bktCur[b4],   a0);
        if (a1>0) sm.sc.shc[b4+1] = atomicAdd(&bktCur[b4+1], a1);
        if (a2>0) sm.sc.shc[b4+2] = atomicAdd(&bktCur[b4+2], a2);
        if (a3>0) sm.sc.shc[b4+3] = atomicAdd(&bktCur[b4+3], a3);
        __syncthreads();
        for (int i=t; i<CH; i+=256){
            long e = e0 + i;
            int slot, keep, s;
            if (e < EDT){ keep = mask_dt[e]; s = ei_dt[e]; slot = ei_dt[EDT+e]; }
            else { long e2 = e-EDT; keep = 1; s = ei_tt[e2]; slot = NT + ei_tt[ETT+e2]; }
            if (keep){
                int b = slot>>9;
                int pos = atomicAdd(&sm.sc.slcur[b], 1);
                sm.sc.stage[pos] = (unsigned)s | ((unsigned)(slot & 511) << 18);
            }
        }
        __syncthreads();
        for (int i=t; i<totKept; i+=256){
            int lo=0, hi=NBKT-1;
            while (lo<hi){ int mid=(lo+hi+1)>>1; if (sm.sc.sloff[mid]<=i) lo=mid; else hi=mid-1; }
            ebuf[sm.sc.shc[lo] + (i - sm.sc.sloff[lo])] = sm.sc.stage[i];
        }
    } else if (blk < NBLK_SCAT + NBLK_STEM){
        // ---- task stem: xt + fused @tt_Wl -> xl_tt ----
        int isbf = *flag;
        if (t < 192) sm.st.sW[t] = ldf(stem_t_W, t, isbf);
        if (t < 16){ sm.st.sb[t]=ldf(stem_t_b,t,isbf); sm.st.sg[t]=ldf(ln_t_g,t,isbf); sm.st.sbt[t]=ldf(ln_t_b,t,isbf); }
        sm.st.sWl[t]     = ldf(tt_Wl, t,     isbf);
        sm.st.sWl[t+256] = ldf(tt_Wl, t+256, isbf);
        __syncthreads();
        long i = (long)(blk - NBLK_SCAT)*256 + t;
        float f[12];
        if (isbf){
            // vectorized: 24B row as 3 x uint2 (8B-aligned: i*24 % 8 == 0)
            const uint2* xp2 = (const uint2*)((const char*)x_tasks + i*24);
            uint2 a0 = xp2[0], a1 = xp2[1], a2 = xp2[2];
            f[0]=ulo(a0.x); f[1]=uhi(a0.x); f[2]=ulo(a0.y); f[3]=uhi(a0.y);
            f[4]=ulo(a1.x); f[5]=uhi(a1.x); f[6]=ulo(a1.y); f[7]=uhi(a1.y);
            f[8]=ulo(a2.x); f[9]=uhi(a2.x); f[10]=ulo(a2.y); f[11]=uhi(a2.y);
        } else {
            #pragma unroll
            for (int k=0;k<12;k++) f[k] = ((const float*)x_tasks)[i*12+k];
        }
        float h[16];
        #pragma unroll
        for (int c=0;c<16;c++){
            float a = sm.st.sb[c];
            #pragma unroll
            for (int k=0;k<12;k++) a += f[k]*sm.st.sW[k*16+c];
            h[c]=a;
        }
        float mu=0.f;
        #pragma unroll
        for (int c=0;c<16;c++) mu += h[c];
        mu *= (1.f/16.f);
        float var=0.f;
        #pragma unroll
        for (int c=0;c<16;c++){ float d=h[c]-mu; var += d*d; }
        var *= (1.f/16.f);
        float inv = rsqrtf(var + 1e-5f);
        float v[16];
        #pragma unroll
        for (int c=0;c<16;c++){
            float y = sm.st.sg[c]*(h[c]-mu)*inv + sm.st.sbt[c];
            v[c] = fin((y>0.f) ? y : 0.01f*y);
        }
        float4* xp = (float4*)(xt + i*16);
        #pragma unroll
        for (int q=0;q<4;q++) xp[q] = make_float4(v[q*4],v[q*4+1],v[q*4+2],v[q*4+3]);
        float o[32];
        #pragma unroll
        for (int c=0;c<32;c++) o[c]=0.f;
        #pragma unroll
        for (int k=0;k<16;k++){
            float xv=v[k];
            #pragma unroll
            for (int c=0;c<32;c++) o[c] += xv*sm.st.sWl[k*32+c];
        }
        #pragma unroll
        for (int c=0;c<32;c++) o[c] = fin(o[c]);
        uint4* op = (uint4*)(xl_tt + i*16);
        #pragma unroll
        for (int q=0;q<4;q++)
            op[q] = make_uint4(pk2(o[q*8],o[q*8+1]), pk2(o[q*8+2],o[q*8+3]),
                               pk2(o[q*8+4],o[q*8+5]), pk2(o[q*8+6],o[q*8+7]));
    } else {
        // ---- data stem: fused @dt_Wl -> xl_dt ----
        int isbf = *flag;
        if (t < 80) sm.sd.sW[t] = ldf(stem_d_W, t, isbf);
        if (t < 16){ sm.sd.sb[t]=ldf(stem_d_b,t,isbf); sm.sd.sg[t]=ldf(ln_d_g,t,isbf); sm.sd.sbt[t]=ldf(ln_d_b,t,isbf); }
        sm.sd.sWl[t]     = ldf(dt_Wl, t,     isbf);
        sm.sd.sWl[t+256] = ldf(dt_Wl, t+256, isbf);
        __syncthreads();
        long i = (long)(blk - NBLK_SCAT - NBLK_STEM)*256 + t;
        float f[5];
        #pragma unroll
        for (int k=0;k<5;k++) f[k] = ldf(x_data, i*5+k, isbf);
        float h[16];
        #pragma unroll
        for (int c=0;c<16;c++){
            float a = sm.sd.sb[c];
            #pragma unroll
            for (int k=0;k<5;k++) a += f[k]*sm.sd.sW[k*16+c];
            h[c]=a;
        }
        float mu=0.f;
        #pragma unroll
        for (int c=0;c<16;c++) mu += h[c];
        mu *= (1.f/16.f);
        float var=0.f;
        #pragma unroll
        for (int c=0;c<16;c++){ float d=h[c]-mu; var += d*d; }
        var *= (1.f/16.f);
        float inv = rsqrtf(var + 1e-5f);
        float v[16];
        #pragma unroll
        for (int c=0;c<16;c++){
            float y = sm.sd.sg[c]*(h[c]-mu)*inv + sm.sd.sbt[c];
            v[c] = (y>0.f) ? y : 0.01f*y;
        }
        float o[32];
        #pragma unroll
        for (int c=0;c<32;c++) o[c]=0.f;
        #pragma unroll
        for (int k=0;k<16;k++){
            float xv=v[k];
            #pragma unroll
            for (int c=0;c<32;c++) o[c] += xv*sm.sd.sWl[k*32+c];
        }
        #pragma unroll
        for (int c=0;c<32;c++) o[c] = fin(o[c]);
        uint4* op = (uint4*)(xl_dt + i*16);
        #pragma unroll
        for (int q=0;q<4;q++)
            op[q] = make_uint4(pk2(o[q*8],o[q*8+1]), pk2(o[q*8+2],o[q*8+3]),
                               pk2(o[q*8+4],o[q*8+5]), pk2(o[q*8+6],o[q*8+7]));
    }
}

// ---------------- phase 2: per-bucket LDS CSR + head-serial GAT aggregation ----------------
// agg output is bf16x2-packed ([NSLOT,8] uints) to halve write + fuse_pool read.
__global__ __launch_bounds__(256) void bucket_aggregate_kernel(
    const int* __restrict__ bktCur, const unsigned* __restrict__ ebuf,
    const float* __restrict__ xt,
    const unsigned* __restrict__ xl_dt, const unsigned* __restrict__ xl_tt,
    const void* __restrict__ dt_Wr, const void* __restrict__ tt_Wr,
    const void* __restrict__ dt_att, const void* __restrict__ tt_att,
    unsigned* __restrict__ agg, const int* __restrict__ flag)
{
    __shared__ float sWr[512], satt[32];
    __shared__ int scnt[SPB], soff[SPB], scur[SPB], spart[256];
    __shared__ unsigned slist[BCAP];
    __shared__ float sspill[256*17];
    int t = threadIdx.x;
    int b = blockIdx.x;
    int which = (b >= NBKT/2);
    int isbf = *flag;
    const void* Wr  = which ? tt_Wr  : dt_Wr;
    const void* att = which ? tt_att : dt_att;
    sWr[t]     = ldf(Wr, t,     isbf);
    sWr[t+256] = ldf(Wr, t+256, isbf);
    if (t < 32) satt[t] = ldf(att, t, isbf);
    scnt[t] = 0; scnt[t+256] = 0;
    __syncthreads();
    int base = b*BCAP;
    int ecnt = bktCur[b] - base;
    if (ecnt > BCAP) ecnt = BCAP;
    if (ecnt < 0) ecnt = 0;
    for (int i=t; i<ecnt; i+=256)
        atomicAdd(&scnt[ebuf[base+i] >> 18], 1);
    __syncthreads();
    int c0 = scnt[2*t], c1 = scnt[2*t+1];
    int ls = c0 + c1;
    spart[t] = ls;
    __syncthreads();
    for (int off=1; off<256; off<<=1){
        int x = spart[t];
        int add = (t>=off) ? spart[t-off] : 0;
        __syncthreads();
        spart[t] = x + add;
        __syncthreads();
    }
    int run = spart[t] - ls;
    soff[2*t] = run; scur[2*t] = run;
    soff[2*t+1] = run + c0; scur[2*t+1] = run + c0;
    __syncthreads();
    for (int i=t; i<ecnt; i+=256){
        unsigned p = ebuf[base+i];
        int pos = atomicAdd(&scur[p >> 18], 1);
        slist[pos] = p & 0x3FFFFu;
    }
    __syncthreads();
    const unsigned* xl = which ? xl_tt : xl_dt;
    #pragma unroll 1
    for (int half=0; half<2; half++){
        int dloc = t + half*256;
        long slot = (long)b*SPB + dloc;
        long d = which ? slot - NT : slot;
        int e0 = soff[dloc], e1 = scur[dloc];
        #pragma unroll 1
        for (int head=0; head<2; head++){
            const float4* xp = (const float4*)(xt + d*16);
            float4 x0=xp[0], x1=xp[1], x2=xp[2], x3=xp[3];
            float xtv[16] = {x0.x,x0.y,x0.z,x0.w, x1.x,x1.y,x1.z,x1.w,
                             x2.x,x2.y,x2.z,x2.w, x3.x,x3.y,x3.z,x3.w};
            float xr[16];
            #pragma unroll
            for (int c=0;c<16;c++) xr[c]=0.f;
            #pragma unroll
            for (int k=0;k<16;k++){
                float xv=xtv[k];
                #pragma unroll
                for (int c=0;c<16;c++) xr[c] += xv*sWr[k*32 + head*16 + c];
            }
            const float* at = satt + head*16;
            float acc[16];
            #pragma unroll
            for (int c=0;c<16;c++) acc[c]=0.f;
            float den=0.f;
            for (int e=e0; e<e1; e++){
                long s = slist[e];
                const uint4* p = (const uint4*)(xl + s*16 + head*8);
                uint4 u0 = p[0], u1 = p[1];
                float sc = score8(u0, xr, at) + score8(u1, xr+8, at+8);
                float a = expf(fminf(fin(sc), 60.f));
                den += a;
                acc8(u0, a, acc); acc8(u1, a, acc+8);
            }
            float id = 1.f/fmaxf(den, 1e-16f);
            if (head==0){
                #pragma unroll
                for (int c=0;c<16;c++) sspill[t*17+c] = acc[c]*id;
            } else {
                float v[16];
                #pragma unroll
                for (int c=0;c<16;c++)
                    v[c] = fin(0.5f*(sspill[t*17+c] + acc[c]*id));
                uint4* op = (uint4*)(agg + slot*8);
                op[0] = make_uint4(pk2(v[0],v[1]),  pk2(v[2],v[3]),
                                   pk2(v[4],v[5]),  pk2(v[6],v[7]));
                op[1] = make_uint4(pk2(v[8],v[9]),  pk2(v[10],v[11]),
                                   pk2(v[12],v[13]),pk2(v[14],v[15]));
            }
        }
    }
}

// ---------------- fuse + pooling + last-block finish ----------------
__global__ __launch_bounds__(256) void fuse_pool_kernel(
    const float* __restrict__ xt,
    const unsigned* __restrict__ agg_dt, const unsigned* __restrict__ agg_tt,
    const void* __restrict__ dt_res, const void* __restrict__ dt_bias,
    const void* __restrict__ tt_res, const void* __restrict__ tt_bias,
    const void* __restrict__ ln1g, const void* __restrict__ ln1b,
    const void* __restrict__ ln2g, const void* __restrict__ ln2b,
    const int* __restrict__ b_tasks, const int* __restrict__ ptrg,
    float* __restrict__ pool_sums, float* __restrict__ pool_cnt,
    int* __restrict__ done,
    void* __restrict__ out, const int* __restrict__ flag)
{
    int isbf = *flag;
    __shared__ float sdt[256], stt[256], sdb[16], stb[16], s1g[16], s1b[16], s2g[16], s2b[16];
    __shared__ float swave[4*48];
    __shared__ int sptr[16];
    __shared__ int s_nonuni;
    __shared__ int s_last;
    int t = threadIdx.x;
    sdt[t] = ldf(dt_res, t, isbf);
    stt[t] = ldf(tt_res, t, isbf);
    if (t < 16){
        sdb[t]=ldf(dt_bias,t,isbf); stb[t]=ldf(tt_bias,t,isbf);
        s1g[t]=ldf(ln1g,t,isbf); s1b[t]=ldf(ln1b,t,isbf);
        s2g[t]=ldf(ln2g,t,isbf); s2b[t]=ldf(ln2b,t,isbf);
        sptr[t]=ptrg[t];
    }
    if (t==0) s_nonuni = 0;
    __syncthreads();
    long i = blockIdx.x*256 + t;
    const float4* xp = (const float4*)(xt + i*16);
    float4 x0=xp[0], x1=xp[1], x2=xp[2], x3=xp[3];
    float xv[16], tupd[16], dupd[16];
    xv[0]=x0.x; xv[1]=x0.y; xv[2]=x0.z; xv[3]=x0.w;
    xv[4]=x1.x; xv[5]=x1.y; xv[6]=x1.z; xv[7]=x1.w;
    xv[8]=x2.x; xv[9]=x2.y; xv[10]=x2.z; xv[11]=x2.w;
    xv[12]=x3.x; xv[13]=x3.y; xv[14]=x3.z; xv[15]=x3.w;
    {
        const uint4* ap = (const uint4*)(agg_dt + i*8);
        uint4 u0 = ap[0], u1 = ap[1];
        float ag[16];
        unp8(u0, ag); unp8(u1, ag+8);
        float v[16];
        #pragma unroll
        for (int c=0;c<16;c++){
            float r = sdb[c];
            #pragma unroll
            for (int k=0;k<16;k++) r += xv[k]*sdt[k*16+c];
            v[c] = fin(ag[c] + r);
        }
        float mu=0.f;
        #pragma unroll
        for (int c=0;c<16;c++) mu += v[c];
        mu *= (1.f/16.f);
        float var=0.f;
        #pragma unroll
        for (int c=0;c<16;c++){ float d=v[c]-mu; var += d*d; }
        var *= (1.f/16.f);
        float inv = rsqrtf(var + 1e-5f);
        #pragma unroll
        for (int c=0;c<16;c++){
            float y = s1g[c]*(v[c]-mu)*inv + s1b[c];
            dupd[c] = fin((y>0.f) ? y : 0.01f*y);
        }
    }
    {
        const uint4* ap = (const uint4*)(agg_tt + i*8);
        uint4 u0 = ap[0], u1 = ap[1];
        float ag[16];
        unp8(u0, ag); unp8(u1, ag+8);
        float v[16];
        #pragma unroll
        for (int c=0;c<16;c++){
            float r = stb[c];
            #pragma unroll
            for (int k=0;k<16;k++) r += xv[k]*stt[k*16+c];
            v[c] = fin(ag[c] + r);
        }
        float mu=0.f;
        #pragma unroll
        for (int c=0;c<16;c++) mu += v[c];
        mu *= (1.f/16.f);
        float var=0.f;
        #pragma unroll
        for (int c=0;c<16;c++){ float d=v[c]-mu; var += d*d; }
        var *= (1.f/16.f);
        float inv = rsqrtf(var + 1e-5f);
        #pragma unroll
        for (int c=0;c<16;c++){
            float y = s2g[c]*(v[c]-mu)*inv + s2b[c];
            tupd[c] = fin((y>0.f) ? y : 0.01f*y);
        }
    }
    #pragma unroll
    for (int j=0;j<16;j++) xv[j] = fin(xv[j]);
    #pragma unroll
    for (int g=0; g<16; g++){
        if (i == sptr[g]){
            #pragma unroll
            for (int j=0;j<16;j++){
                stf(out, g*96+j,    xv[j],   isbf);
                stf(out, g*96+16+j, tupd[j], isbf);
                stf(out, g*96+32+j, dupd[j], isbf);
            }
        }
    }
    int gi = b_tasks[i];
    int g0 = b_tasks[blockIdx.x*256];
    if (gi != g0) s_nonuni = 1;
    __syncthreads();
    if (s_nonuni){
        for (int j=0;j<16;j++){
            atomicAdd(&pool_sums[gi*48+j],    xv[j]);
            atomicAdd(&pool_sums[gi*48+16+j], tupd[j]);
            atomicAdd(&pool_sums[gi*48+32+j], dupd[j]);
        }
        atomicAdd(&pool_cnt[gi], 1.f);
    } else {
        int lane = t & 63, wid = t >> 6;
        #pragma unroll
        for (int j=0;j<16;j++){
            float v = xv[j];
            v += __shfl_down(v, 32); v += __shfl_down(v, 16);
            v += __shfl_down(v, 8);  v += __shfl_down(v, 4);
            v += __shfl_down(v, 2);  v += __shfl_down(v, 1);
            if (lane==0) swave[wid*48+j] = v;
        }
        #pragma unroll
        for (int j=0;j<16;j++){
            float v = tupd[j];
            v += __shfl_down(v, 32); v += __shfl_down(v, 16);
            v += __shfl_down(v, 8);  v += __shfl_down(v, 4);
            v += __shfl_down(v, 2);  v += __shfl_down(v, 1);
            if (lane==0) swave[wid*48+16+j] = v;
        }
        #pragma unroll
        for (int j=0;j<16;j++){
            float v = dupd[j];
            v += __shfl_down(v, 32); v += __shfl_down(v, 16);
            v += __shfl_down(v, 8);  v += __shfl_down(v, 4);
            v += __shfl_down(v, 2);  v += __shfl_down(v, 1);
            if (lane==0) swave[wid*48+32+j] = v;
        }
        __syncthreads();
        if (t < 48){
            float s = swave[t] + swave[48+t] + swave[96+t] + swave[144+t];
            atomicAdd(&pool_sums[g0*48+t], s);
        }
        if (t == 0) atomicAdd(&pool_cnt[g0], 256.f);
    }
    __syncthreads();
    if (t == 0){
        __threadfence();
        s_last = (atomicAdd(done, 1) == gridDim.x - 1) ? 1 : 0;
    }
    __syncthreads();
    if (s_last){
        __threadfence();
        for (int j = t; j < 768; j += 256){
            int g = j/48, c = j - g*48;
            stf(out, g*96+48+c, fin(pool_sums[g*48+c]/fmaxf(pool_cnt[g],1.f)), isbf);
        }
    }
}

extern "C" void kernel_launch(void* const* d_in, const int* in_sizes, int n_in,
                              void* d_out, int out_size, void* d_ws, size_t ws_size,
                              hipStream_t stream)
{
    const void* x_tasks  = d_in[0];
    const void* x_data   = d_in[1];
    const void* stem_t_W = d_in[2];
    const void* stem_t_b = d_in[3];
    const void* stem_d_W = d_in[4];
    const void* stem_d_b = d_in[5];
    const void* ln_t_g   = d_in[6];
    const void* ln_t_b   = d_in[7];
    const void* ln_d_g   = d_in[8];
    const void* ln_d_b   = d_in[9];
    const void* dt_Wl    = d_in[10];
    const void* dt_Wr    = d_in[11];
    const void* dt_att   = d_in[12];
    const void* dt_res   = d_in[13];
    const void* dt_bias  = d_in[14];
    const void* tt_Wl    = d_in[15];
    const void* tt_Wr    = d_in[16];
    const void* tt_att   = d_in[17];
    const void* tt_res   = d_in[18];
    const void* tt_bias  = d_in[19];
    const void* ln1_g    = d_in[20];
    const void* ln1_b    = d_in[21];
    const void* ln2_g    = d_in[22];
    const void* ln2_b    = d_in[23];
    const int*  ei_dt    = (const int*)d_in[24];
    const int*  mask_dt  = (const int*)d_in[25];
    const int*  ei_tt    = (const int*)d_in[26];
    const int*  b_tasks  = (const int*)d_in[27];
    const int*  ptrg     = (const int*)d_in[28];

    char* w = (char*)d_ws;
    const size_t MB = 1ull<<20;
    float*    xt        = (float*)(w);              // 16 MB  [NT,16] fp32
    unsigned* xl_dt     = (unsigned*)(w + 16*MB);   // 16 MB  [ND,16] bf16x2-packed
    unsigned* xl_tt     = (unsigned*)(w + 32*MB);   // 16 MB  [NT,16] bf16x2-packed
    unsigned* agg       = (unsigned*)(w + 48*MB);   // 16 MB  [NSLOT,8] bf16x2-packed
    unsigned* ebuf      = (unsigned*)(w + 64*MB);   // 12 MB (NBKT*BCAP) + slack
    int*      bktCur    = (int*)  (w + 77*MB);      // 4 KB
    float*    pool_sums = (float*)(w + 77*MB + 8192);
    float*    pool_cnt  = (float*)(w + 77*MB + 12288);
    int*      flag      = (int*)  (w + 77*MB + 16384);
    int*      done      = (int*)  (w + 77*MB + 16388);

    setup_kernel<<<1, 256, 0, stream>>>((const unsigned*)x_tasks, flag, bktCur,
                                        pool_sums, pool_cnt, done);

    // mega: scatter first (overlaps with stems backfilling behind it)
    mega_kernel<<<NBLK_MEGA, 256, 0, stream>>>(
        x_tasks, x_data, stem_t_W, stem_t_b, ln_t_g, ln_t_b,
        stem_d_W, stem_d_b, ln_d_g, ln_d_b, tt_Wl, dt_Wl,
        xt, xl_tt, xl_dt, ei_dt, mask_dt, ei_tt, bktCur, ebuf, flag);

    // per-bucket LDS CSR + head-serial aggregation (both graphs)
    bucket_aggregate_kernel<<<NBKT, 256, 0, stream>>>(bktCur, ebuf, xt, xl_dt, xl_tt,
        dt_Wr, tt_Wr, dt_att, tt_att, agg, flag);

    // fuse + pool + output (finish folded in via last-block-done)
    fuse_pool_kernel<<<NT/256, 256, 0, stream>>>(xt, agg, agg + (long)NT*8,
        dt_res, dt_bias, tt_res, tt_bias, ln1_g, ln1_b, ln2_g, ln2_b,
        b_tasks, ptrg, pool_sums, pool_cnt, done, d_out, flag);
}